// Round 14
// baseline (192.776 us; speedup 1.0000x reference)
//
#include <hip/hip_runtime.h>
#include <math.h>

#define GDIM 152
#define NA 3
#define GG (GDIM * GDIM)        // 23104
#define EXP_CLAMP 1000.0f
#define NTHREADS 64             // single-wave blocks
#define TILE 256                // cells per tile = 4 * NTHREADS
#define GSTRIDE (TILE + 1)      // 257 float4s between group planes
#define TILES_TOTAL 8664        // 32*3*GG / 256, exact
#define NTPB 4                  // tiles per persistent block
#define NBLK (TILES_TOTAL / NTPB)   // 2166, exact; whole grid resident (<13/CU LDS cap)
// NBLK*TILE = 554,496 cells = 24*GG exactly -> stepping a block's tile by NBLK
// keeps pos/gy/gx0/a invariant (t2 += 24, 24%3==0) and advances both pointers
// by one fixed constant. Loop body = loads + PROC + LDS + stores only.
#define ISTEP ((size_t)24 * 12 * (GG / 4))  // input step, float4 units = 1,663,488
#define OSTEP ((size_t)NBLK * TILE * 3)     // output step, float4 units = 1,663,488

typedef float floatx4 __attribute__((ext_vector_type(4)));

__device__ __forceinline__ float sigmoidf(float v) {
    return 1.0f / (1.0f + __expf(-v));
}

// XOR swizzle on float4 entry index (bijective on [0,256)).
__device__ __forceinline__ int swz(int e) { return e ^ ((e >> 3) & 7); }

// Persistent single-wave blocks with register double-buffered loads: each wave
// computes tile i while tile i+1's 12 dwordx4 loads are in flight. Kills the
// per-wave pipeline-restart overhead (kernarg/addr init + one exposed
// load-latency per short-lived wave) that every ~64us variant shared.
__global__ __launch_bounds__(NTHREADS) void yolo_decode_pers(
    const float* __restrict__ x,
    const float* __restrict__ anchors,
    const int* __restrict__ img_size_p,
    float* __restrict__ out)
{
    __shared__ floatx4 sh[3 * GSTRIDE];   // 12,336 B; 2166 blocks => all resident

    const int t = threadIdx.x;
    const int tilebase = blockIdx.x * TILE;

    const float stride = (float)(*img_size_p) / (float)GDIM;  // 4.0
    const float inv_s = 1.0f / stride;

    // Loop-invariant per-thread context (cells tilebase+4t .. +3, same plane/row)
    const int cbase = tilebase + 4 * t;
    const unsigned t2 = (unsigned)cbase / (unsigned)GG;  // b*NA + a
    const int pos = cbase - (int)t2 * GG;
    const int gy  = pos / GDIM;
    const int gx0 = pos - gy * GDIM;
    const int a   = (int)(t2 % 3u);
    const float gyf = (float)gy;

    const int PS = GG / 4;
    const floatx4* ip = (const floatx4*)x + (size_t)(t2 * 12u) * PS + (pos >> 2);
    floatx4* op = (floatx4*)out + (size_t)tilebase * 3;

    const float ah = anchors[a * 5 + 0] * inv_s * stride;  // matches reference rounding
    const float aw = anchors[a * 5 + 1] * inv_s * stride;
    const float al = anchors[a * 5 + 2] * inv_s * stride;

#define PROCJ(R, J)                                                      \
    do {                                                                 \
        floatx4 o0, o1, o2;                                              \
        o0.x = (sigmoidf(R[0][J]) + (float)(gx0 + (J))) * stride;        \
        o0.y = (sigmoidf(R[1][J]) + gyf) * stride;                       \
        o0.z = sigmoidf(R[2][J]);                                        \
        o0.w = fminf(__expf(R[3][J]), EXP_CLAMP) * ah;                   \
        o1.x = fminf(__expf(R[4][J]), EXP_CLAMP) * aw;                   \
        o1.y = fminf(__expf(R[5][J]), EXP_CLAMP) * al;                   \
        o1.z = R[6][J];                                                  \
        o1.w = R[7][J];                                                  \
        o2.x = sigmoidf(R[8][J]);                                        \
        o2.y = sigmoidf(R[9][J]);                                        \
        o2.z = sigmoidf(R[10][J]);                                       \
        o2.w = sigmoidf(R[11][J]);                                       \
        int e = swz(4 * t + (J));                                        \
        sh[0 * GSTRIDE + e] = o0;                                        \
        sh[1 * GSTRIDE + e] = o1;                                        \
        sh[2 * GSTRIDE + e] = o2;                                        \
    } while (0)

    // barrier -> PROC (LDS transpose) -> barrier -> lane-contiguous stores
#define COMPUTE_STORE(R)                                                 \
    do {                                                                 \
        __syncthreads();                                                 \
        PROCJ(R, 0); PROCJ(R, 1); PROCJ(R, 2); PROCJ(R, 3);              \
        __syncthreads();                                                 \
        _Pragma("unroll")                                                \
        for (int k2 = 0; k2 < 12; ++k2) {                                \
            int F = t + NTHREADS * k2;                                   \
            unsigned cell = (unsigned)F / 3u;                            \
            int g = F - (int)cell * 3;                                   \
            op[F] = sh[g * GSTRIDE + swz((int)cell)];                    \
        }                                                                \
        op += OSTEP;                                                     \
    } while (0)

    floatx4 ra[12], rb[12];
#pragma unroll
    for (int k = 0; k < 12; ++k) ra[k] = ip[k * PS];   // tile 0 loads
    ip += ISTEP;
#pragma unroll
    for (int k = 0; k < 12; ++k) rb[k] = ip[k * PS];   // tile 1 loads in flight
    ip += ISTEP;

    COMPUTE_STORE(ra);                                 // tile 0 (waits only on ra)
#pragma unroll
    for (int k = 0; k < 12; ++k) ra[k] = ip[k * PS];   // tile 2 loads
    ip += ISTEP;

    COMPUTE_STORE(rb);                                 // tile 1
#pragma unroll
    for (int k = 0; k < 12; ++k) rb[k] = ip[k * PS];   // tile 3 loads

    COMPUTE_STORE(ra);                                 // tile 2
    COMPUTE_STORE(rb);                                 // tile 3
}

extern "C" void kernel_launch(void* const* d_in, const int* in_sizes, int n_in,
                              void* d_out, int out_size, void* d_ws, size_t ws_size,
                              hipStream_t stream) {
    const float* x        = (const float*)d_in[0];
    const float* anchors  = (const float*)d_in[1];
    const int*   img_size = (const int*)d_in[2];
    float*       out      = (float*)d_out;

    yolo_decode_pers<<<NBLK, NTHREADS, 0, stream>>>(x, anchors, img_size, out);
}